// Round 4
// baseline (239.704 us; speedup 1.0000x reference)
//
#include <hip/hip_runtime.h>
#include <hip/hip_bf16.h>
#include <cmath>

#define NB 8
#define NN 2048
#define FIN 128
#define FOUT 64
#define GAT_ALPHA 0.2f

typedef __attribute__((ext_vector_type(8))) short short8;
typedef __attribute__((ext_vector_type(4))) float f32x4;

static __device__ __forceinline__ ushort f2bf(float x) {
    __hip_bfloat16 hb = __float2bfloat16(x);
    return __builtin_bit_cast(ushort, hb);
}
static __device__ __forceinline__ short8 pack8(const float4 a, const float4 b) {
    short8 r;
    r[0] = (short)f2bf(a.x); r[1] = (short)f2bf(a.y); r[2] = (short)f2bf(a.z); r[3] = (short)f2bf(a.w);
    r[4] = (short)f2bf(b.x); r[5] = (short)f2bf(b.y); r[6] = (short)f2bf(b.z); r[7] = (short)f2bf(b.w);
    return r;
}

// ---- Kernel 0: WT[o][k] = bf16(W[k][o]);  wa1 = W@a1, wa2 = W@a2 (fp32) ----
__global__ void wt_kernel(const float* __restrict__ W, const float* __restrict__ a1,
                          const float* __restrict__ a2, ushort* __restrict__ WT,
                          float* __restrict__ wa) {
    const int t = threadIdx.x;
    const int o = t & 63, kg = t >> 6;
#pragma unroll
    for (int kk = 0; kk < 32; ++kk) {               // independent loads: ILP-bound
        const int k = kg * 32 + kk;
        WT[o * FIN + k] = f2bf(W[k * FOUT + o]);
    }
    // wa: each thread does a 32-long half-dot, combine with partner lane
    const int k = t >> 1, hf = t & 1;
    float x1 = 0.f, x2 = 0.f;
#pragma unroll
    for (int oo = 0; oo < 32; ++oo) {
        const int o2 = hf * 32 + oo;
        const float w = W[k * FOUT + o2];
        x1 = fmaf(w, a1[o2], x1);
        x2 = fmaf(w, a2[o2], x2);
    }
    x1 += __shfl_xor(x1, 1);
    x2 += __shfl_xor(x2, 1);
    if (hf == 0) { wa[k] = x1; wa[FIN + k] = x2; }
}

// ---- Kernel A: Wh via MFMA -> whT[b][o][j] bf16;  s1 = h@wa1 (wave1), s2 = h@wa2 (wave2) ----
__global__ __launch_bounds__(256) void wh_kernel(const float* __restrict__ h,
                                                 const ushort* __restrict__ WT,
                                                 const float* __restrict__ wa,
                                                 ushort* __restrict__ whT,
                                                 float* __restrict__ s1,
                                                 float* __restrict__ s2) {
    const int t = threadIdx.x, w = t >> 6, lane = t & 63;
    const int rrow = lane & 15, kg = lane >> 4;
    const int j0 = blockIdx.x * 16;              // global row base (never crosses batch)
    const int b = j0 >> 11, jloc = j0 & (NN - 1);
    const float* hrow = h + (size_t)(j0 + rrow) * FIN + kg * 8;

    float4 hv[8];
    short8 af[4];
#pragma unroll
    for (int ks = 0; ks < 4; ++ks) {
        hv[2 * ks]     = *(const float4*)(hrow + ks * 32);
        hv[2 * ks + 1] = *(const float4*)(hrow + ks * 32 + 4);
        af[ks] = pack8(hv[2 * ks], hv[2 * ks + 1]);
    }
    f32x4 acc = {0.f, 0.f, 0.f, 0.f};
#pragma unroll
    for (int ks = 0; ks < 4; ++ks) {
        const short8 bf = *(const short8*)(WT + (size_t)(w * 16 + rrow) * FIN + ks * 32 + kg * 8);
        acc = __builtin_amdgcn_mfma_f32_16x16x32_bf16(af[ks], bf, acc, 0, 0, 0);
    }
#pragma unroll
    for (int q = 0; q < 4; ++q)
        whT[(((size_t)b * FOUT + w * 16 + rrow) << 11) + jloc + kg * 4 + q] = f2bf(acc[q]);

    if (w == 1 || w == 2) {   // s1 on wave1, s2 on wave2, in parallel (exact fp32)
        const float* wap = wa + (w == 2 ? FIN : 0);
        float p = 0.f;
#pragma unroll
        for (int ks = 0; ks < 4; ++ks) {
#pragma unroll
            for (int e = 0; e < 8; ++e) {
                const float4 hq = hv[2 * ks + (e >> 2)];
                const float x = (e & 3) == 0 ? hq.x : (e & 3) == 1 ? hq.y : (e & 3) == 2 ? hq.z : hq.w;
                p = fmaf(x, wap[ks * 32 + kg * 8 + e], p);
            }
        }
        p += __shfl_xor(p, 16); p += __shfl_xor(p, 32);
        if (lane < 16) {
            if (w == 1) s1[j0 + lane] = p; else s2[j0 + lane] = p;
        }
    }
}

// ---- Kernel B: fused mask + no-max softmax + MFMA PV over a j-half; partial num/den ----
__global__ __launch_bounds__(256) void attn_kernel(const int* __restrict__ adj,
                                                   const ushort* __restrict__ whT,
                                                   const float* __restrict__ s1,
                                                   const float* __restrict__ s2,
                                                   float* __restrict__ pnum,
                                                   float* __restrict__ pden) {
    __shared__ float red[4 * 16 * FOUT];   // 16 KB epilogue reduction only
    __shared__ float denl[4][16];
    const int t = threadIdx.x, w = t >> 6, lane = t & 63;
    const int rrow = lane & 15, kg = lane >> 4;
    const int b = blockIdx.x >> 8, blk = blockIdx.x & 255;
    const int i0 = (blk >> 1) << 4, half = blk & 1;
    const int jh = half * (NN / 2);

    const float s1v = s1[b * NN + i0 + rrow];
    const float* s2g = s2 + b * NN + jh;                 // L1-resident, no LDS stage
    const int* adjRow = adj + ((size_t)(b * NN + i0 + rrow)) * NN + jh;
    const ushort* whB = whT + (size_t)b * FOUT * NN + jh;
    const int jb0 = w * 256 + kg * 8;

    short8 ones;
#pragma unroll
    for (int r = 0; r < 8; ++r) ones[r] = (short)0x3F80;  // bf16 1.0

    f32x4 acc[4] = {{0,0,0,0},{0,0,0,0},{0,0,0,0},{0,0,0,0}};
    f32x4 accd = {0,0,0,0};

    // distance-1 software pipeline: all step inputs ping-pong in registers
    int4   ab[2][2];
    float4 sb[2][2];
    short8 wb[2][4];
    ab[0][0] = *(const int4*)(adjRow + jb0);
    ab[0][1] = *(const int4*)(adjRow + jb0 + 4);
    sb[0][0] = *(const float4*)(s2g + jb0);
    sb[0][1] = *(const float4*)(s2g + jb0 + 4);
#pragma unroll
    for (int nt = 0; nt < 4; ++nt)
        wb[0][nt] = *(const short8*)(whB + ((nt * 16 + rrow) << 11) + jb0);

#pragma unroll
    for (int step = 0; step < 8; ++step) {
        const int cur = step & 1, nxt = cur ^ 1;
        if (step < 7) {
            const int jb = jb0 + (step + 1) * 32;
            ab[nxt][0] = *(const int4*)(adjRow + jb);
            ab[nxt][1] = *(const int4*)(adjRow + jb + 4);
            sb[nxt][0] = *(const float4*)(s2g + jb);
            sb[nxt][1] = *(const float4*)(s2g + jb + 4);
#pragma unroll
            for (int nt = 0; nt < 4; ++nt)
                wb[nxt][nt] = *(const short8*)(whB + ((nt * 16 + rrow) << 11) + jb);
        }
        const int   aa[8] = {ab[cur][0].x, ab[cur][0].y, ab[cur][0].z, ab[cur][0].w,
                             ab[cur][1].x, ab[cur][1].y, ab[cur][1].z, ab[cur][1].w};
        const float ss[8] = {sb[cur][0].x, sb[cur][0].y, sb[cur][0].z, sb[cur][0].w,
                             sb[cur][1].x, sb[cur][1].y, sb[cur][1].z, sb[cur][1].w};
        short8 af;
#pragma unroll
        for (int r = 0; r < 8; ++r) {
            const float x = s1v + ss[r];
            const float e = __expf(fmaxf(x, GAT_ALPHA * x));  // no-max softmax: |score| bounded
            af[r] = (short)f2bf(aa[r] > 0 ? e : 0.f);
        }
#pragma unroll
        for (int nt = 0; nt < 4; ++nt)
            acc[nt] = __builtin_amdgcn_mfma_f32_16x16x32_bf16(af, wb[cur][nt], acc[nt], 0, 0, 0);
        accd = __builtin_amdgcn_mfma_f32_16x16x32_bf16(af, ones, accd, 0, 0, 0);  // row-sum = den
    }

#pragma unroll
    for (int nt = 0; nt < 4; ++nt)
#pragma unroll
        for (int q = 0; q < 4; ++q)
            red[(w * 16 + kg * 4 + q) * FOUT + nt * 16 + rrow] = acc[nt][q];
    if (rrow == 0) {
#pragma unroll
        for (int q = 0; q < 4; ++q) denl[w][kg * 4 + q] = accd[q];
    }
    __syncthreads();

    const size_t obase = (((size_t)half * NB + b) * NN + i0) * FOUT;
#pragma unroll
    for (int rep = 0; rep < 4; ++rep) {
        const int idx = rep * 256 + t;
        const int r = idx >> 6, o = idx & 63;
        pnum[obase + (size_t)r * FOUT + o] = red[r * FOUT + o] + red[(16 + r) * FOUT + o]
                                          + red[(32 + r) * FOUT + o] + red[(48 + r) * FOUT + o];
    }
    if (t < 16) pden[((size_t)half * NB + b) * NN + i0 + t] =
        denl[0][t] + denl[1][t] + denl[2][t] + denl[3][t];
}

// ---- Kernel C: combine halves, normalize, ELU ----
__global__ __launch_bounds__(256) void reduce_kernel(const float* __restrict__ pnum,
                                                     const float* __restrict__ pden,
                                                     float* __restrict__ out) {
    const int idx = blockIdx.x * 256 + threadIdx.x;
    const int bi = idx >> 6;
    const float num = pnum[idx] + pnum[idx + (size_t)NB * NN * FOUT];
    const float d = pden[bi] + pden[bi + NB * NN];
    const float v = num / d;
    out[idx] = v > 0.f ? v : expm1f(v);
}

extern "C" void kernel_launch(void* const* d_in, const int* in_sizes, int n_in,
                              void* d_out, int out_size, void* d_ws, size_t ws_size,
                              hipStream_t stream) {
    const float* h   = (const float*)d_in[0];
    const int*   adj = (const int*)d_in[1];
    const float* W   = (const float*)d_in[2];
    const float* a1  = (const float*)d_in[3];
    const float* a2  = (const float*)d_in[4];
    float* out = (float*)d_out;

    char* ws = (char*)d_ws;
    ushort* whT = (ushort*)ws;  ws += (size_t)NB * FOUT * NN * sizeof(ushort);   // 2 MB
    ushort* WT  = (ushort*)ws;  ws += (size_t)FOUT * FIN * sizeof(ushort);       // 16 KB
    float*  wa  = (float*)ws;   ws += (size_t)2 * FIN * sizeof(float);           // 1 KB
    float*  s1  = (float*)ws;   ws += (size_t)NB * NN * sizeof(float);
    float*  s2  = (float*)ws;   ws += (size_t)NB * NN * sizeof(float);
    float*  pnum = (float*)ws;  ws += (size_t)2 * NB * NN * FOUT * sizeof(float); // 8 MB
    float*  pden = (float*)ws;  ws += (size_t)2 * NB * NN * sizeof(float);

    wt_kernel<<<1, 256, 0, stream>>>(W, a1, a2, WT, wa);
    wh_kernel<<<NB * NN / 16, 256, 0, stream>>>(h, WT, wa, whT, s1, s2);
    attn_kernel<<<NB * 256, 256, 0, stream>>>(adj, whT, s1, s2, pnum, pden);
    reduce_kernel<<<NB * NN * FOUT / 256, 256, 0, stream>>>(pnum, pden, out);
}